// Round 15
// baseline (58.852 us; speedup 1.0000x reference)
//
#include <hip/hip_runtime.h>

// QKV attention, N=4 H=8 C=64 T=2048, fp32 in/out, bf16 MFMA internally.
// R15: R12 base (best passing, 58.3us) + V-prep fold. R13/R14's K-direct
// failed twice (asm-load outputs consumed by register-only MFMA across the
// loop back-edge — compiler copy/wait semantics unverifiable headlessly);
// abandoned. This round: V is staged directly from the original fp32 qkv
// (no transpose needed), converted bf16 via cvt_pk at the publish step
// (after vmcnt(0), before barrier — same sync skeleton as R12, asm outputs
// still consumed only by memory ops after drain-all). Prep kernel shrinks
// to K-transpose only (50.4 -> 25.2 MB, 768 -> 256 blocks).

typedef __bf16 bf8v __attribute__((ext_vector_type(8)));
typedef float f16v __attribute__((ext_vector_type(16)));
typedef int i4 __attribute__((ext_vector_type(4)));

#define SEQ 2048
#define DD 64
#define NHEADS 32
#define QBLK 128
#define SBLK 64
#define NTILES 32             // s-tiles total; 16 per s-group
#define TILEK (SBLK * DD)     // elements per K/V tile (4096)
#define NTHR 512

// scale = 1/sqrt(sqrt(64)) on both q and k; log2(e) folded into q's side
#define KSC 0.35355339059327373f
#define QSC (0.35355339059327373f * 1.4426950408889634f)

#if __has_builtin(__builtin_amdgcn_exp2f)
#define EXP2(x) __builtin_amdgcn_exp2f(x)
#else
#define EXP2(x) exp2f(x)
#endif

__device__ __forceinline__ void gload16(i4& dst, const void* p) {
    asm volatile("global_load_dwordx4 %0, %1, off" : "=&v"(dst) : "v"(p));
}

#define SBAR() __builtin_amdgcn_sched_barrier(0)
// drain-all: correct regardless of compiler-inserted vmem ops (spill-safe)
#define VMWAIT0() do { asm volatile("s_waitcnt vmcnt(0)" ::: "memory"); SBAR(); } while (0)

// packed f32->bf16 convert (T12 recipe, learn_hip-verified)
__device__ __forceinline__ unsigned cvtpk(float a, float b) {
    unsigned r;
    asm("v_cvt_pk_bf16_f32 %0, %1, %2" : "=v"(r) : "v"(a), "v"(b));
    return r;
}

// 8 fp32 (two i4 bit-views) -> 8 bf16 packed in one i4
union F4V { i4 i; float f[4]; };
__device__ __forceinline__ i4 packbf(i4 a, i4 b) {
    F4V ua, ub; ua.i = a; ub.i = b;
    i4 w;
    w.x = (int)cvtpk(ua.f[0], ua.f[1]);
    w.y = (int)cvtpk(ua.f[2], ua.f[3]);
    w.z = (int)cvtpk(ub.f[0], ub.f[1]);
    w.w = (int)cvtpk(ub.f[2], ub.f[3]);
    return w;
}

// hi-half lane exchange (verified R8): a = {a_lo, b_lo'}, b = {a_hi', b_hi}
#if __has_builtin(__builtin_amdgcn_permlane32_swap)
typedef int i2v __attribute__((ext_vector_type(2)));
__device__ __forceinline__ void plswap(unsigned& a, unsigned& b) {
    i2v r = __builtin_amdgcn_permlane32_swap((int)a, (int)b, false, false);
    a = (unsigned)r.x;
    b = (unsigned)r.y;
}
#else
__device__ __forceinline__ void plswap(unsigned& a, unsigned& b) {
    asm volatile("v_permlane32_swap_b32 %0, %1" : "+v"(a), "+v"(b));
}
#endif

// ---------------- prep: K only — fp32 -> bf16, transposed + scaled ----------
__global__ void prep_kernel(const float* __restrict__ qkv, __bf16* __restrict__ KT) {
    const int bx = blockIdx.x, tid = threadIdx.x;
    const int head = bx >> 3, sblk = bx & 7;
    const int b = head >> 3, h = head & 7;
    const float* kp = qkv + (size_t)(b * 1536 + 512 + h * 64) * SEQ;
    __bf16* dst = KT + (size_t)head * SEQ * DD;
    const int s = sblk * 256 + tid;
#pragma unroll
    for (int c0 = 0; c0 < DD; c0 += 8) {
        bf8v v;
#pragma unroll
        for (int j = 0; j < 8; ++j)
            v[j] = (__bf16)(kp[(size_t)(c0 + j) * SEQ + s] * KSC);
        *(bf8v*)(dst + (size_t)s * DD + c0) = v;
    }
}

// swizzled LDS fragment read: row r (64 elem = 128 B rows), 16B chunk c16
// stored at position c16 ^ (r & 7)
__device__ __forceinline__ bf8v ldswz(const __bf16* base, int r, int c16) {
    return *(const bf8v*)(base + r * DD + (((c16) ^ (r & 7)) << 3));
}

__global__ __launch_bounds__(NTHR, 4) void attn_kernel(
    const float* __restrict__ qkv, const __bf16* __restrict__ KT,
    float* __restrict__ out)
{
    // 64KB pool: K/V tiles for 2 s-groups x double-buffer; combine overlays it.
    __shared__ __align__(16) char pool[65536];
    __bf16* KLg = (__bf16*)pool;                 // [grp*2+buf][TILEK]
    __bf16* VLg = (__bf16*)(pool + 32768);       // [grp*2+buf][TILEK]
    float* comb  = (float*)pool;                 // [128][65] fp32 overlay
    float* combl = (float*)(pool + 33280);       // [128] fp32

    const int tid = threadIdx.x;
    const int wid = tid >> 6;
    const int gg  = wid >> 2;          // s-group 0/1
    const int qw  = wid & 3;           // q-wave within group
    const int lane = tid & 63;
    const int hi = lane >> 5;
    const int l31 = lane & 31;

    // XCD-bijective swizzle: 512 blocks, 8 XCDs -> 64-block chunks = 4 heads/XCD
    const int bid = blockIdx.x;
    const int bx = (bid & 7) * 64 + (bid >> 3);
    const int head = bx >> 4;
    const int t0 = (bx & 15) * QBLK;
    const int b = head >> 3, h = head & 7;

    const float* qp = qkv + (size_t)(b * 1536 + h * 64) * SEQ;
    const __bf16* kt = KT + (size_t)head * SEQ * DD;
    const float* vp = qkv + (size_t)(b * 1536 + 1024 + h * 64) * SEQ;  // fp32 V
    float* op = out + (size_t)head * DD * SEQ;

    // ---- staging geometry (per s-group: 256 threads cover the 64-row tile) --
    const int g256 = tid & 255;
    const int sp  = g256 & 7;          // 16B-chunk position within row (8 bf16)
    const int sr  = g256 >> 3;         // 0..31
    const int scs = sp ^ (sr & 7);     // source chunk (involution; same for sr+32)
    const __bf16* kg0 = kt + sr * DD + (scs << 3);
    const __bf16* kg1 = kt + (sr + 32) * DD + (scs << 3);
    // V source: 8 consecutive fp32 (32B) per slot = two 16B loads
    const float* vg0 = vp + (size_t)sr * SEQ + (scs << 3);
    const float* vg1 = vp + (size_t)(sr + 32) * SEQ + (scs << 3);
    const int l0 = sr * DD + (sp << 3);
    const int l1 = (sr + 32) * DD + (sp << 3);

    i4 rk0, rk1, rv0a, rv0b, rv1a, rv1b;

    // ---- prologue: issue group's tile(gg) loads; Q convert overlaps flight --
    SBAR();
    gload16(rk0, kg0 + gg * TILEK);
    gload16(rk1, kg1 + gg * TILEK);
    gload16(rv0a, vg0 + gg * SBLK);
    gload16(rv0b, vg0 + gg * SBLK + 4);
    gload16(rv1a, vg1 + gg * SBLK);
    gload16(rv1b, vg1 + gg * SBLK + 4);
    SBAR();

    // Q B-fragments for 32x32x16: col = t = l31, k = c = kb*16 + hi*8 + j
    const int tq = t0 + qw * 32 + l31;
    bf8v qf[4];
#pragma unroll
    for (int kb = 0; kb < 4; ++kb) {
        bf8v q;
#pragma unroll
        for (int j = 0; j < 8; ++j)
            q[j] = (__bf16)(qp[(size_t)(kb * 16 + hi * 8 + j) * SEQ + tq] * QSC);
        qf[kb] = q;
    }

    f16v Oacc[2];
    Oacc[0] = (f16v)0.0f;
    Oacc[1] = (f16v)0.0f;
    float lp[4] = {0.f, 0.f, 0.f, 0.f};

    VMWAIT0();
    {
        __bf16* k0 = KLg + (2 * gg) * TILEK;
        __bf16* v0 = VLg + (2 * gg) * TILEK;
        *(i4*)&k0[l0] = rk0;  *(i4*)&k0[l1] = rk1;
        *(i4*)&v0[l0] = packbf(rv0a, rv0b);
        *(i4*)&v0[l1] = packbf(rv1a, rv1b);
    }
    __syncthreads();

    // ---- main loop: 16 iterations, group gg computes tiles 2*it+gg ----
    for (int it = 0; it < NTILES / 2; ++it) {
        const int cb = it & 1;
        const __bf16* kcu = KLg + (2 * gg + cb) * TILEK;
        const __bf16* vcu = VLg + (2 * gg + cb) * TILEK;
        const bool more = (it + 1 < NTILES / 2);

        // pinned issue of the group's next tile; latency hides under compute
        if (more) {
            const int tg = 2 * (it + 1) + gg;
            SBAR();
            gload16(rk0, kg0 + tg * TILEK);
            gload16(rk1, kg1 + tg * TILEK);
            gload16(rv0a, vg0 + tg * SBLK);
            gload16(rv0b, vg0 + tg * SBLK + 4);
            gload16(rv1a, vg1 + tg * SBLK);
            gload16(rv1b, vg1 + tg * SBLK + 4);
            SBAR();
        }

        // ---- QK^T + softmax, sequential over sb (caps live regs: one S) ----
        // S^T rows s = sb*32 + (reg&3) + 8*(reg>>2) + 4*hi, col t = l31
        unsigned pd[2][4][2];
#pragma unroll
        for (int sb = 0; sb < 2; ++sb) {
            f16v S = (f16v)0.0f;
            __builtin_amdgcn_s_setprio(1);
#pragma unroll
            for (int kb = 0; kb < 4; ++kb) {
                bf8v a = ldswz(kcu, sb * 32 + l31, 2 * kb + hi);
                S = __builtin_amdgcn_mfma_f32_32x32x16_bf16(a, qf[kb], S, 0, 0, 0);
            }
            __builtin_amdgcn_s_setprio(0);

            // exps via hazard-safe builtin; sums in f32; bf16 pack via cvt_pk
#pragma unroll
            for (int q = 0; q < 4; ++q) {
                float e0 = EXP2(S[4 * q + 0]);
                float e1 = EXP2(S[4 * q + 1]);
                float e2 = EXP2(S[4 * q + 2]);
                float e3 = EXP2(S[4 * q + 3]);
                lp[q] += (e0 + e1) + (e2 + e3);
                pd[sb][q][0] = cvtpk(e0, e1);
                pd[sb][q][1] = cvtpk(e2, e3);
            }
        }

        // hi-half exchange -> complete PV B-frags in-register
#pragma unroll
        for (int sb = 0; sb < 2; ++sb)
#pragma unroll
            for (int m = 0; m < 2; ++m) {
                plswap(pd[sb][2 * m][0], pd[sb][2 * m + 1][0]);
                plswap(pd[sb][2 * m][1], pd[sb][2 * m + 1][1]);
            }

        // ---- mid-iteration sync: land next tile, publish to buf^1, barrier --
        if (more) {
            VMWAIT0();
            __bf16* kn = KLg + (2 * gg + (cb ^ 1)) * TILEK;
            __bf16* vn = VLg + (2 * gg + (cb ^ 1)) * TILEK;
            *(i4*)&kn[l0] = rk0;  *(i4*)&kn[l1] = rk1;
            *(i4*)&vn[l0] = packbf(rv0a, rv0b);
            *(i4*)&vn[l1] = packbf(rv1a, rv1b);
            __syncthreads();
        }

        // VALU(permlane)->MFMA-read hazard guard for the no-barrier last iter
        asm volatile("s_nop 2" :::);

        // ---- PV: O[c][t] += V[c][s] P^T[s][t]; V frags loaded per-kb ----
        __builtin_amdgcn_s_setprio(1);
#pragma unroll
        for (int sb = 0; sb < 2; ++sb)
#pragma unroll
            for (int m = 0; m < 2; ++m) {
                const int kb = 2 * sb + m;
                union { unsigned u[4]; bf8v b; } f;
                f.u[0] = pd[sb][2 * m][0];
                f.u[1] = pd[sb][2 * m][1];
                f.u[2] = pd[sb][2 * m + 1][0];
                f.u[3] = pd[sb][2 * m + 1][1];
                bf8v v0 = ldswz(vcu, l31,      2 * kb + hi);
                bf8v v1 = ldswz(vcu, 32 + l31, 2 * kb + hi);
                Oacc[0] = __builtin_amdgcn_mfma_f32_32x32x16_bf16(v0, f.b, Oacc[0], 0, 0, 0);
                Oacc[1] = __builtin_amdgcn_mfma_f32_32x32x16_bf16(v1, f.b, Oacc[1], 0, 0, 0);
            }
        __builtin_amdgcn_s_setprio(0);
    }

    // ---- combine the two s-halves through LDS (overlay on K/V pool) ----
    float lg = (lp[0] + lp[1]) + (lp[2] + lp[3]);
    lg += __shfl_xor(lg, 32);          // full half-sum for this t-column

    __syncthreads();                   // everyone done with K/V LDS
    const int qcol = qw * 32 + l31;    // 0..127
    if (gg == 1) {
#pragma unroll
        for (int cbk = 0; cbk < 2; ++cbk)
#pragma unroll
            for (int r = 0; r < 16; ++r) {
                const int c = cbk * 32 + (r & 3) + 8 * (r >> 2) + 4 * hi;
                comb[qcol * 65 + c] = Oacc[cbk][r];
            }
        if (hi == 0) combl[qcol] = lg;
    }
    __syncthreads();
    if (gg == 0) {
        const float rl = 1.0f / (lg + combl[qcol]);
#pragma unroll
        for (int cbk = 0; cbk < 2; ++cbk)
#pragma unroll
            for (int r = 0; r < 16; ++r) {
                const int c = cbk * 32 + (r & 3) + 8 * (r >> 2) + 4 * hi;
                const float o = Oacc[cbk][r] + comb[qcol * 65 + c];
                op[(size_t)c * SEQ + tq] = o * rl;
            }
    }
}

extern "C" void kernel_launch(void* const* d_in, const int* in_sizes, int n_in,
                              void* d_out, int out_size, void* d_ws, size_t ws_size,
                              hipStream_t stream) {
    const float* qkv = (const float*)d_in[0];
    float* out = (float*)d_out;
    __bf16* KT = (__bf16*)d_ws;                         // [32][2048][64] bf16, 8.4 MB
    prep_kernel<<<dim3(256), dim3(256), 0, stream>>>(qkv, KT);
    attn_kernel<<<dim3(NHEADS * (SEQ / QBLK)), dim3(NTHR), 0, stream>>>(qkv, KT, out);
}